// Round 1
// 666.063 us; speedup vs baseline: 1.0241x; 1.0241x over previous
//
#include <hip/hip_runtime.h>
#include <cstdint>

#define C_DIM 1024
#define N_DIM 36864   // 192*192

typedef unsigned short ushort_t;
typedef __attribute__((ext_vector_type(8))) short bf16x8;   // 8 bf16 in 4 VGPRs
typedef __attribute__((ext_vector_type(4))) float f32x4;

__device__ __forceinline__ ushort_t f2b(float f) {
    unsigned u = __float_as_uint(f);
    u = (u + 0x7fffu + ((u >> 16) & 1u)) >> 16;   // RN-even
    return (ushort_t)u;
}
__device__ __forceinline__ float b2f(ushort_t b) {
    return __uint_as_float(((unsigned)b) << 16);
}

// async global->LDS, 16B per lane; lds base must be wave-uniform, HW adds lane*16
__device__ __forceinline__ void async16(const void* g, const void* lds) {
    __builtin_amdgcn_global_load_lds(
        (const __attribute__((address_space(1))) unsigned int*)(uintptr_t)g,
        (__attribute__((address_space(3))) unsigned int*)(uint32_t)(uintptr_t)lds,
        16, 0, 0);
}

// LDS tile layout for GEMM operands: [rows][32] ushorts (64 B rows).
// Bank-conflict swizzle: 16B segment s of row r lives at segment (s ^ ((r>>1)&3)).
// global_load_lds writes linearly, so we pre-permute the GLOBAL source column per
// lane (segments permuted within the same 64B row -> coalescing unchanged) and
// apply the same XOR on the ds_read side.  8-way conflict -> 2-way (free).

// ---------------- K1a (fallback): x -> Ph, Pl ----------------
__global__ __launch_bounds__(256) void k_convert(const float* __restrict__ x,
                                                 ushort_t* __restrict__ ph,
                                                 ushort_t* __restrict__ pl) {
    int i = blockIdx.x * 256 + threadIdx.x;        // float4 index
    float4 v = ((const float4*)x)[i];
    ushort4 h, l;
    h.x = f2b(v.x); l.x = f2b(v.x - b2f(h.x));
    h.y = f2b(v.y); l.y = f2b(v.y - b2f(h.y));
    h.z = f2b(v.z); l.z = f2b(v.z - b2f(h.z));
    h.w = f2b(v.w); l.w = f2b(v.w - b2f(h.w));
    ((ushort4*)ph)[i] = h;
    ((ushort4*)pl)[i] = l;
}

// ---------------- K1b (preferred): x -> Ph, Pl, PhT in one pass ----------------
__global__ __launch_bounds__(256) void k_convtrans(const float* __restrict__ x,
                                                   ushort_t* __restrict__ ph,
                                                   ushort_t* __restrict__ pl,
                                                   ushort_t* __restrict__ pht) {
    __shared__ __align__(16) ushort_t th[64][72];
    const int t = threadIdx.x;
    const int i = t >> 2, qd = t & 3;
    const int c0 = blockIdx.y << 6;
    const size_t n0 = (size_t)blockIdx.x << 6;

    const size_t row = (size_t)(c0 + i) * N_DIM + n0 + (qd << 4);
    const float* src = x + row;
    union { ushort_t s[16]; uint4 q[2]; } H, Lo;
#pragma unroll
    for (int u4 = 0; u4 < 4; ++u4) {
        float4 v = ((const float4*)src)[u4];
        ushort_t h0 = f2b(v.x), h1 = f2b(v.y), h2 = f2b(v.z), h3 = f2b(v.w);
        H.s[u4 * 4 + 0] = h0; Lo.s[u4 * 4 + 0] = f2b(v.x - b2f(h0));
        H.s[u4 * 4 + 1] = h1; Lo.s[u4 * 4 + 1] = f2b(v.y - b2f(h1));
        H.s[u4 * 4 + 2] = h2; Lo.s[u4 * 4 + 2] = f2b(v.z - b2f(h2));
        H.s[u4 * 4 + 3] = h3; Lo.s[u4 * 4 + 3] = f2b(v.w - b2f(h3));
    }
    *(uint4*)(ph + row)     = H.q[0];
    *(uint4*)(ph + row + 8) = H.q[1];
    *(uint4*)(pl + row)     = Lo.q[0];
    *(uint4*)(pl + row + 8) = Lo.q[1];
    *(uint4*)&th[i][qd << 4]       = H.q[0];
    *(uint4*)&th[i][(qd << 4) + 8] = H.q[1];
    __syncthreads();

    ushort_t tmp[16];
#pragma unroll
    for (int u = 0; u < 16; ++u) tmp[u] = th[(qd << 4) + u][i];
    ushort_t* dst = pht + (n0 + i) * C_DIM + c0 + (qd << 4);
    *(uint4*)dst       = *(uint4*)tmp;
    *(uint4*)(dst + 8) = *(uint4*)(tmp + 8);
}

// ---------------- K2: E-GEMM partials. G1 = Ph*Ph^T, G2 = Ph*Pl^T ----------------
// tile 128(c) x 128(d), BK=32, 4 waves of 64x64, dual MFMA chain, split-K over gridDim.z
// double-buffered LDS, raw s_barrier + partial vmcnt (prefetch never drained),
// XOR-swizzled LDS (pre-swizzled global source + swizzled ds_read)
__global__ __launch_bounds__(256, 2) void k_egemm(const ushort_t* __restrict__ ph,
                                                  const ushort_t* __restrict__ pl,
                                                  float* __restrict__ g1,
                                                  float* __restrict__ g2,
                                                  int kchunk) {
    __shared__ __align__(16) ushort_t sA [2][128 * 32];   // 16 KB
    __shared__ __align__(16) ushort_t sBh[2][128 * 32];   // 16 KB
    __shared__ __align__(16) ushort_t sBl[2][128 * 32];   // 16 KB

    const int t = threadIdx.x;
    const int w = t >> 6;
    const int L = t & 63;
    const int c0 = blockIdx.x << 7;
    const int d0 = blockIdx.y << 7;
    const int kb = blockIdx.z * kchunk;
    const int lrow = L >> 2;
    const int lcol = (((L & 3) ^ ((L >> 3) & 3)) << 3);   // seg ^ row[2:1], in ushorts

    // wave w stages rows [32w, 32w+32) of A, Bh, Bl (2 async16 chunks each)
    const ushort_t* gA0 = ph + (size_t)(c0 + (w << 5) + lrow) * N_DIM + kb + lcol;
    const ushort_t* gH0 = ph + (size_t)(d0 + (w << 5) + lrow) * N_DIM + kb + lcol;
    const ushort_t* gL0 = pl + (size_t)(d0 + (w << 5) + lrow) * N_DIM + kb + lcol;
    ushort_t* lA[2] = { sA[0]  + (w << 10), sA[1]  + (w << 10) };
    ushort_t* lH[2] = { sBh[0] + (w << 10), sBh[1] + (w << 10) };
    ushort_t* lL[2] = { sBl[0] + (w << 10), sBl[1] + (w << 10) };

    const int wm = (w >> 1) << 6;   // wave row offset (c) 0/64
    const int wn = (w & 1) << 6;    // wave col offset (d) 0/64
    const int lm = L & 15, q = L >> 4;
    const int co = ((q ^ ((lm >> 1) & 3)) << 3);   // swizzled k-segment for reads

    f32x4 acc1[4][4], acc2[4][4];
#pragma unroll
    for (int a = 0; a < 4; ++a)
#pragma unroll
        for (int b = 0; b < 4; ++b) { acc1[a][b] = (f32x4)0.0f; acc2[a][b] = (f32x4)0.0f; }

    auto stage = [&](int ti, int b) {
        const ushort_t* ga = gA0 + (ti << 5);
        const ushort_t* gh = gH0 + (ti << 5);
        const ushort_t* gl = gL0 + (ti << 5);
        async16(ga,              lA[b]);
        async16(ga + 16 * N_DIM, lA[b] + 512);
        async16(gh,              lH[b]);
        async16(gh + 16 * N_DIM, lH[b] + 512);
        async16(gl,              lL[b]);
        async16(gl + 16 * N_DIM, lL[b] + 512);
    };

    const int nIter = kchunk >> 5;
    stage(0, 0);

    for (int ti = 0; ti < nIter; ++ti) {
        const int cb = ti & 1;
        if (ti + 1 < nIter) {
            stage(ti + 1, cb ^ 1);
            __builtin_amdgcn_s_waitcnt(0x0F76);   // vmcnt(6): tile ti landed; prefetch stays in flight
        } else {
            __builtin_amdgcn_s_waitcnt(0x0F70);   // vmcnt(0): last tile landed
        }
        __builtin_amdgcn_s_barrier();

        bf16x8 a[4], bh[4], bl[4];
#pragma unroll
        for (int mt = 0; mt < 4; ++mt)
            a[mt] = *(const bf16x8*)(sA[cb] + ((wm + (mt << 4) + lm) << 5) + co);
#pragma unroll
        for (int nt = 0; nt < 4; ++nt) {
            bh[nt] = *(const bf16x8*)(sBh[cb] + ((wn + (nt << 4) + lm) << 5) + co);
            bl[nt] = *(const bf16x8*)(sBl[cb] + ((wn + (nt << 4) + lm) << 5) + co);
        }
#pragma unroll
        for (int mt = 0; mt < 4; ++mt)
#pragma unroll
            for (int nt = 0; nt < 4; ++nt) {
                acc1[mt][nt] = __builtin_amdgcn_mfma_f32_16x16x32_bf16(a[mt], bh[nt], acc1[mt][nt], 0, 0, 0);
                acc2[mt][nt] = __builtin_amdgcn_mfma_f32_16x16x32_bf16(a[mt], bl[nt], acc2[mt][nt], 0, 0, 0);
            }
        // all 12 ds_reads consumed by MFMA above (lgkm waits inserted by compiler),
        // so after this barrier it is safe for the next iter to overwrite buffer cb^1
        __builtin_amdgcn_s_barrier();
    }

    const size_t zb = (size_t)blockIdx.z << 20;
#pragma unroll
    for (int mt = 0; mt < 4; ++mt)
#pragma unroll
        for (int nt = 0; nt < 4; ++nt)
#pragma unroll
            for (int r = 0; r < 4; ++r) {
                int cg = c0 + wm + (mt << 4) + (q << 2) + r;   // D row = (L>>4)*4 + reg
                int dg = d0 + wn + (nt << 4) + lm;             // D col = L&15
                size_t o = zb + ((size_t)cg << 10) + dg;
                g1[o] = acc1[mt][nt][r];
                g2[o] = acc2[mt][nt][r];
            }
}

// ---------------- K3: E = sum_z (G1 + G2) + (sum_z G2)^T, 64x64 tiles ----------------
__global__ __launch_bounds__(256) void k_reduce(const float* __restrict__ g1,
                                                const float* __restrict__ g2,
                                                float* __restrict__ E,
                                                int splitk) {
    __shared__ float ld[64][65];
    const int t = threadIdx.x;
    const int i = t >> 2;              // row 0..63
    const int jb = (t & 3) << 4;       // col chunk base 0/16/32/48
    const int c0 = blockIdx.y << 6;
    const int d0 = blockIdx.x << 6;

    float acc[16];
#pragma unroll
    for (int u = 0; u < 16; ++u) acc[u] = 0.0f;

    for (int z = 0; z < splitk; ++z) {
        const size_t zb = (size_t)z << 20;
        const float* p1 = g1 + zb + ((size_t)(c0 + i) << 10) + d0 + jb;
        const float* p2 = g2 + zb + ((size_t)(c0 + i) << 10) + d0 + jb;
        const float* pt = g2 + zb + ((size_t)(d0 + i) << 10) + c0 + jb;
#pragma unroll
        for (int u4 = 0; u4 < 4; ++u4) {
            float4 v1 = ((const float4*)p1)[u4];
            float4 v2 = ((const float4*)p2)[u4];
            acc[u4 * 4 + 0] += v1.x + v2.x;
            acc[u4 * 4 + 1] += v1.y + v2.y;
            acc[u4 * 4 + 2] += v1.z + v2.z;
            acc[u4 * 4 + 3] += v1.w + v2.w;
        }
        __syncthreads();   // previous iter's LDS reads done
#pragma unroll
        for (int u4 = 0; u4 < 4; ++u4)
            *(float4*)&ld[i][jb + u4 * 4] = ((const float4*)pt)[u4];
        __syncthreads();
#pragma unroll
        for (int u = 0; u < 16; ++u)
            acc[u] += ld[jb + u][i];   // g2[d0+jb+u][c0+i]
    }

    float* eo = E + ((size_t)(c0 + i) << 10) + d0 + jb;
#pragma unroll
    for (int u4 = 0; u4 < 4; ++u4) {
        float4 v;
        v.x = acc[u4 * 4 + 0]; v.y = acc[u4 * 4 + 1];
        v.z = acc[u4 * 4 + 2]; v.w = acc[u4 * 4 + 3];
        ((float4*)eo)[u4] = v;
    }
}

// ---------------- K4: row softmax: A = softmax(rowmin(E) - E) ----------------
__global__ __launch_bounds__(256) void k_softmax(const float* __restrict__ E,
                                                 ushort_t* __restrict__ att) {
    const int c = blockIdx.x;
    const int t = threadIdx.x;
    __shared__ float red[4];
    __shared__ float bcast;

    float4 e4 = ((const float4*)E)[((size_t)c << 8) + t];
    float m = fminf(fminf(e4.x, e4.y), fminf(e4.z, e4.w));
#pragma unroll
    for (int off = 32; off > 0; off >>= 1) m = fminf(m, __shfl_down(m, off));
    if ((t & 63) == 0) red[t >> 6] = m;
    __syncthreads();
    if (t == 0) bcast = fminf(fminf(red[0], red[1]), fminf(red[2], red[3]));
    __syncthreads();
    m = bcast;

    float w0 = expf(m - e4.x), w1 = expf(m - e4.y);
    float w2 = expf(m - e4.z), w3 = expf(m - e4.w);
    float s = w0 + w1 + w2 + w3;
#pragma unroll
    for (int off = 32; off > 0; off >>= 1) s += __shfl_down(s, off);
    if ((t & 63) == 0) red[t >> 6] = s;
    __syncthreads();
    if (t == 0) bcast = red[0] + red[1] + red[2] + red[3];
    __syncthreads();
    float inv = 1.0f / bcast;
    ushort4 o;
    o.x = f2b(w0 * inv); o.y = f2b(w1 * inv);
    o.z = f2b(w2 * inv); o.w = f2b(w3 * inv);
    ((ushort4*)att)[((size_t)c << 8) + t] = o;
}

// ---------------- K5 (fallback): transpose Ph -> PhT ----------------
__global__ __launch_bounds__(256) void k_transpose(const ushort_t* __restrict__ ph,
                                                   ushort_t* __restrict__ pht) {
    __shared__ __align__(16) ushort_t tile[64][72];
    const int t = threadIdx.x;
    const int i = t >> 2, qd = t & 3;
    const int c0 = blockIdx.y << 6;
    const size_t n0 = (size_t)blockIdx.x << 6;

    const ushort_t* src = ph + (size_t)(c0 + i) * N_DIM + n0 + (qd << 4);
    uint4 v0 = *(const uint4*)src;
    uint4 v1 = *(const uint4*)(src + 8);
    *(uint4*)&tile[i][qd << 4]       = v0;
    *(uint4*)&tile[i][(qd << 4) + 8] = v1;
    __syncthreads();

    ushort_t tmp[16];
#pragma unroll
    for (int u = 0; u < 16; ++u) tmp[u] = tile[(qd << 4) + u][i];
    ushort_t* dst = pht + (n0 + i) * C_DIM + c0 + (qd << 4);
    *(uint4*)dst       = *(uint4*)tmp;
    *(uint4*)(dst + 8) = *(uint4*)(tmp + 8);
}

// ---------------- K6: O = A * P, out = gamma*O + x. 128x128 tile, 4 waves of 64x64 ----------------
__global__ __launch_bounds__(256) void k_ogemm(const ushort_t* __restrict__ att,
                                               const ushort_t* __restrict__ pht,
                                               const float* __restrict__ x,
                                               const float* __restrict__ gamma,
                                               float* __restrict__ out) {
    __shared__ __align__(16) ushort_t sA[128 * 32];
    __shared__ __align__(16) ushort_t sB[128 * 32];

    const int t = threadIdx.x;
    const int w = t >> 6, L = t & 63;
    const int n0 = blockIdx.x << 7;
    const int c0 = blockIdx.y << 7;
    const int srow = L >> 2;
    const int scol = (((L & 3) ^ ((L >> 3) & 3)) << 3);   // swizzled source segment

    const int wm = (w >> 1) << 6, wn = (w & 1) << 6;
    const int lm = L & 15, q = L >> 4;
    const int co = ((q ^ ((lm >> 1) & 3)) << 3);          // swizzled read segment

    f32x4 acc[4][4];
#pragma unroll
    for (int a = 0; a < 4; ++a)
#pragma unroll
        for (int b = 0; b < 4; ++b) acc[a][b] = (f32x4)0.0f;

    for (int k = 0; k < C_DIM; k += 32) {
#pragma unroll
        for (int j = 0; j < 4; ++j) {
            int ch = (w << 2) + j;                    // 0..7 -> sA rows, 8..15 -> sB rows
            int row = ((ch & 7) << 4) + srow;
            const ushort_t* src = (ch < 8)
                ? att + (size_t)(c0 + row) * C_DIM + k + scol
                : pht + (size_t)(n0 + row) * C_DIM + k + scol;
            ushort_t* base = (ch < 8) ? sA : sB;
            async16(src, base + (((ch & 7) << 4) << 5));
        }
        __syncthreads();

        bf16x8 a[4], b[4];
#pragma unroll
        for (int mt = 0; mt < 4; ++mt)
            a[mt] = *(const bf16x8*)(sA + ((wm + (mt << 4) + lm) << 5) + co);
#pragma unroll
        for (int nt = 0; nt < 4; ++nt)
            b[nt] = *(const bf16x8*)(sB + ((wn + (nt << 4) + lm) << 5) + co);
#pragma unroll
        for (int mt = 0; mt < 4; ++mt)
#pragma unroll
            for (int nt = 0; nt < 4; ++nt)
                acc[mt][nt] = __builtin_amdgcn_mfma_f32_16x16x32_bf16(a[mt], b[nt], acc[mt][nt], 0, 0, 0);
        __syncthreads();
    }

    const float g = gamma[0];
#pragma unroll
    for (int mt = 0; mt < 4; ++mt)
#pragma unroll
        for (int nt = 0; nt < 4; ++nt)
#pragma unroll
            for (int r = 0; r < 4; ++r) {
                int cg = c0 + wm + (mt << 4) + (q << 2) + r;
                int ng = n0 + wn + (nt << 4) + lm;
                size_t o = (size_t)cg * N_DIM + ng;
                out[o] = g * acc[mt][nt][r] + x[o];
            }
}

extern "C" void kernel_launch(void* const* d_in, const int* in_sizes, int n_in,
                              void* d_out, int out_size, void* d_ws, size_t ws_size,
                              hipStream_t stream) {
    const float* x     = (const float*)d_in[0];
    const float* gamma = (const float*)d_in[1];
    float* out = (float*)d_out;
    char* ws = (char*)d_ws;

    const size_t P = 75497472ull, SL = 4194304ull, EB = 4194304ull, AT = 2097152ull;

    // preferred: fused convert+transpose (needs 3 P-arrays) with S=8
    int S = 8;
    bool fused = (ws_size >= 3 * P + (size_t)S * 2 * SL + EB + AT);
    if (!fused) {
        if (ws_size < 2 * P + (size_t)S * 2 * SL + EB + AT) S = 4;
        if (ws_size < 2 * P + (size_t)S * 2 * SL + EB + AT) S = 3;
    }
    const int kchunk = N_DIM / S;

    if (fused) {
        ushort_t* ph  = (ushort_t*)(ws);
        ushort_t* pl  = (ushort_t*)(ws + P);
        ushort_t* pht = (ushort_t*)(ws + 2 * P);
        float*    g1  = (float*)   (ws + 3 * P);
        float*    g2  = (float*)   (ws + 3 * P + (size_t)S * SL);
        float*    E   = (float*)   (ws + 3 * P + (size_t)S * 2 * SL);
        ushort_t* att = (ushort_t*)(ws + 3 * P + (size_t)S * 2 * SL + EB);

        k_convtrans<<<dim3(N_DIM / 64, C_DIM / 64), 256, 0, stream>>>(x, ph, pl, pht);
        k_egemm<<<dim3(8, 8, S), 256, 0, stream>>>(ph, pl, g1, g2, kchunk);
        k_reduce<<<dim3(16, 16), 256, 0, stream>>>(g1, g2, E, S);
        k_softmax<<<dim3(C_DIM), 256, 0, stream>>>(E, att);
        k_ogemm<<<dim3(N_DIM / 128, C_DIM / 128), 256, 0, stream>>>(att, pht, x, gamma, out);
    } else {
        ushort_t* ph  = (ushort_t*)(ws);
        ushort_t* pl  = (ushort_t*)(ws + P);
        float*    g1  = (float*)   (ws + 2 * P);
        float*    g2  = (float*)   (ws + 2 * P + (size_t)S * SL);
        float*    E   = (float*)   (ws + 2 * P + (size_t)S * 2 * SL);
        ushort_t* att = (ushort_t*)(ws + 2 * P + (size_t)S * 2 * SL + EB);
        ushort_t* pht = pl;   // transpose written after E-GEMM has consumed Pl

        k_convert<<<dim3((C_DIM * (size_t)N_DIM / 4) / 256), 256, 0, stream>>>(x, ph, pl);
        k_egemm<<<dim3(8, 8, S), 256, 0, stream>>>(ph, pl, g1, g2, kchunk);
        k_reduce<<<dim3(16, 16), 256, 0, stream>>>(g1, g2, E, S);
        k_softmax<<<dim3(C_DIM), 256, 0, stream>>>(E, att);
        k_transpose<<<dim3(N_DIM / 64, C_DIM / 64), 256, 0, stream>>>(ph, pht);
        k_ogemm<<<dim3(N_DIM / 128, C_DIM / 128), 256, 0, stream>>>(att, pht, x, gamma, out);
    }
}

// Round 2
// 628.377 us; speedup vs baseline: 1.0855x; 1.0600x over previous
//
#include <hip/hip_runtime.h>
#include <cstdint>

#define C_DIM 1024
#define N_DIM 36864   // 192*192

typedef unsigned short ushort_t;
typedef __attribute__((ext_vector_type(8))) short bf16x8;   // 8 bf16 in 4 VGPRs
typedef __attribute__((ext_vector_type(4))) float f32x4;

__device__ __forceinline__ ushort_t f2b(float f) {
    unsigned u = __float_as_uint(f);
    u = (u + 0x7fffu + ((u >> 16) & 1u)) >> 16;   // RN-even
    return (ushort_t)u;
}
__device__ __forceinline__ float b2f(ushort_t b) {
    return __uint_as_float(((unsigned)b) << 16);
}

// async global->LDS, 16B per lane; lds base must be wave-uniform, HW adds lane*16
__device__ __forceinline__ void async16(const void* g, const void* lds) {
    __builtin_amdgcn_global_load_lds(
        (const __attribute__((address_space(1))) unsigned int*)(uintptr_t)g,
        (__attribute__((address_space(3))) unsigned int*)(uint32_t)(uintptr_t)lds,
        16, 0, 0);
}

// LDS tile layout for GEMM operands: [rows][32] ushorts (64 B rows).
// Bank-conflict swizzle: 16B segment s of row r lives at segment (s ^ ((r>>1)&3)).
// global_load_lds writes linearly, so we pre-permute the GLOBAL source column per
// lane (segments permuted within the same 64B row -> coalescing unchanged) and
// apply the same XOR on the ds_read side.  8-way conflict -> 2-way (free).

// ---------------- K1a (fallback): x -> Ph, Pl ----------------
__global__ __launch_bounds__(256) void k_convert(const float* __restrict__ x,
                                                 ushort_t* __restrict__ ph,
                                                 ushort_t* __restrict__ pl) {
    int i = blockIdx.x * 256 + threadIdx.x;        // float4 index
    float4 v = ((const float4*)x)[i];
    ushort4 h, l;
    h.x = f2b(v.x); l.x = f2b(v.x - b2f(h.x));
    h.y = f2b(v.y); l.y = f2b(v.y - b2f(h.y));
    h.z = f2b(v.z); l.z = f2b(v.z - b2f(h.z));
    h.w = f2b(v.w); l.w = f2b(v.w - b2f(h.w));
    ((ushort4*)ph)[i] = h;
    ((ushort4*)pl)[i] = l;
}

// ---------------- K1b (preferred): x -> Ph, Pl, PhT in one pass ----------------
__global__ __launch_bounds__(256) void k_convtrans(const float* __restrict__ x,
                                                   ushort_t* __restrict__ ph,
                                                   ushort_t* __restrict__ pl,
                                                   ushort_t* __restrict__ pht) {
    __shared__ __align__(16) ushort_t th[64][72];
    const int t = threadIdx.x;
    const int i = t >> 2, qd = t & 3;
    const int c0 = blockIdx.y << 6;
    const size_t n0 = (size_t)blockIdx.x << 6;

    const size_t row = (size_t)(c0 + i) * N_DIM + n0 + (qd << 4);
    const float* src = x + row;
    union { ushort_t s[16]; uint4 q[2]; } H, Lo;
#pragma unroll
    for (int u4 = 0; u4 < 4; ++u4) {
        float4 v = ((const float4*)src)[u4];
        ushort_t h0 = f2b(v.x), h1 = f2b(v.y), h2 = f2b(v.z), h3 = f2b(v.w);
        H.s[u4 * 4 + 0] = h0; Lo.s[u4 * 4 + 0] = f2b(v.x - b2f(h0));
        H.s[u4 * 4 + 1] = h1; Lo.s[u4 * 4 + 1] = f2b(v.y - b2f(h1));
        H.s[u4 * 4 + 2] = h2; Lo.s[u4 * 4 + 2] = f2b(v.z - b2f(h2));
        H.s[u4 * 4 + 3] = h3; Lo.s[u4 * 4 + 3] = f2b(v.w - b2f(h3));
    }
    *(uint4*)(ph + row)     = H.q[0];
    *(uint4*)(ph + row + 8) = H.q[1];
    *(uint4*)(pl + row)     = Lo.q[0];
    *(uint4*)(pl + row + 8) = Lo.q[1];
    *(uint4*)&th[i][qd << 4]       = H.q[0];
    *(uint4*)&th[i][(qd << 4) + 8] = H.q[1];
    __syncthreads();

    ushort_t tmp[16];
#pragma unroll
    for (int u = 0; u < 16; ++u) tmp[u] = th[(qd << 4) + u][i];
    ushort_t* dst = pht + (n0 + i) * C_DIM + c0 + (qd << 4);
    *(uint4*)dst       = *(uint4*)tmp;
    *(uint4*)(dst + 8) = *(uint4*)(tmp + 8);
}

// ---------------- K2: triangular E-GEMM partials over 36 tile-pairs ----------------
// E = Ph*Ph^T + (Ph*Pl^T + Pl*Ph^T); both addends symmetric -> only upper pairs.
// Per pair (c0<=d0): acc1 = Ph_c*Ph_d^T, acc2 = Ph_c*Pl_d^T + Pl_c*Ph_d^T.
// tile 128x128, BK=32, 4 waves of 64x64, 3 MFMA chains, split-K over gridDim.z.
// Compact output: g[(z*36+pair)*16384 + r*128 + c].
__global__ __launch_bounds__(256, 2) void k_egemm(const ushort_t* __restrict__ ph,
                                                  const ushort_t* __restrict__ pl,
                                                  float* __restrict__ g1,
                                                  float* __restrict__ g2,
                                                  int kchunk) {
    __shared__ __align__(16) ushort_t sAh[2][128 * 32];   // 16 KB each
    __shared__ __align__(16) ushort_t sAl[2][128 * 32];
    __shared__ __align__(16) ushort_t sBh[2][128 * 32];
    __shared__ __align__(16) ushort_t sBl[2][128 * 32];   // 64 KB total -> 2 blocks/CU

    const int t = threadIdx.x;
    const int w = t >> 6;
    const int L = t & 63;

    // pair decode: blockIdx.x in [0,36) -> (pi <= pj) over 8x8 128-tiles
    int pr = blockIdx.x, pi = 0;
    while (pr >= 8 - pi) { pr -= 8 - pi; ++pi; }
    const int c0 = pi << 7;
    const int d0 = (pi + pr) << 7;

    const int kb = blockIdx.z * kchunk;
    const int lrow = L >> 2;
    const int lcol = (((L & 3) ^ ((L >> 3) & 3)) << 3);   // pre-swizzled source segment

    const size_t rA = (size_t)(c0 + (w << 5) + lrow) * N_DIM + kb + lcol;
    const size_t rB = (size_t)(d0 + (w << 5) + lrow) * N_DIM + kb + lcol;
    const ushort_t* gAh = ph + rA;
    const ushort_t* gAl = pl + rA;
    const ushort_t* gBh = ph + rB;
    const ushort_t* gBl = pl + rB;
    const int wb = w << 10;   // wave's 32-row slice in each LDS panel

    const int wm = (w >> 1) << 6;   // wave row offset (c) 0/64
    const int wn = (w & 1) << 6;    // wave col offset (d) 0/64
    const int lm = L & 15, q = L >> 4;
    const int co = ((q ^ ((lm >> 1) & 3)) << 3);   // swizzled k-segment for reads

    f32x4 acc1[4][4], acc2[4][4];
#pragma unroll
    for (int a = 0; a < 4; ++a)
#pragma unroll
        for (int b = 0; b < 4; ++b) { acc1[a][b] = (f32x4)0.0f; acc2[a][b] = (f32x4)0.0f; }

    auto stage = [&](int ti, int b) {
        const int o = ti << 5;
        async16(gAh + o,              sAh[b] + wb);
        async16(gAh + o + 16 * N_DIM, sAh[b] + wb + 512);
        async16(gAl + o,              sAl[b] + wb);
        async16(gAl + o + 16 * N_DIM, sAl[b] + wb + 512);
        async16(gBh + o,              sBh[b] + wb);
        async16(gBh + o + 16 * N_DIM, sBh[b] + wb + 512);
        async16(gBl + o,              sBl[b] + wb);
        async16(gBl + o + 16 * N_DIM, sBl[b] + wb + 512);
    };

    const int nIter = kchunk >> 5;
    stage(0, 0);

    for (int ti = 0; ti < nIter; ++ti) {
        const int cb = ti & 1;
        if (ti + 1 < nIter) {
            stage(ti + 1, cb ^ 1);
            __builtin_amdgcn_s_waitcnt(0x0F78);   // vmcnt(8): tile ti landed; prefetch in flight
        } else {
            __builtin_amdgcn_s_waitcnt(0x0F70);   // vmcnt(0): last tile landed
        }
        __builtin_amdgcn_s_barrier();

        bf16x8 ah[4], al[4], bh[4], bl[4];
#pragma unroll
        for (int mt = 0; mt < 4; ++mt) {
            const int ro = ((wm + (mt << 4) + lm) << 5) + co;
            ah[mt] = *(const bf16x8*)(sAh[cb] + ro);
            al[mt] = *(const bf16x8*)(sAl[cb] + ro);
        }
#pragma unroll
        for (int nt = 0; nt < 4; ++nt) {
            const int ro = ((wn + (nt << 4) + lm) << 5) + co;
            bh[nt] = *(const bf16x8*)(sBh[cb] + ro);
            bl[nt] = *(const bf16x8*)(sBl[cb] + ro);
        }
#pragma unroll
        for (int mt = 0; mt < 4; ++mt)
#pragma unroll
            for (int nt = 0; nt < 4; ++nt) {
                acc1[mt][nt] = __builtin_amdgcn_mfma_f32_16x16x32_bf16(ah[mt], bh[nt], acc1[mt][nt], 0, 0, 0);
                acc2[mt][nt] = __builtin_amdgcn_mfma_f32_16x16x32_bf16(ah[mt], bl[nt], acc2[mt][nt], 0, 0, 0);
                acc2[mt][nt] = __builtin_amdgcn_mfma_f32_16x16x32_bf16(al[mt], bh[nt], acc2[mt][nt], 0, 0, 0);
            }
        __builtin_amdgcn_s_barrier();
    }

    const size_t base = ((size_t)blockIdx.z * 36 + blockIdx.x) << 14;
#pragma unroll
    for (int mt = 0; mt < 4; ++mt)
#pragma unroll
        for (int nt = 0; nt < 4; ++nt)
#pragma unroll
            for (int r = 0; r < 4; ++r) {
                int lr = wm + (mt << 4) + (q << 2) + r;   // row within 128-tile (c)
                int lc = wn + (nt << 4) + lm;             // col within 128-tile (d)
                size_t o = base + ((size_t)lr << 7) + lc;
                g1[o] = acc1[mt][nt][r];
                g2[o] = acc2[mt][nt][r];
            }
}

// ---------------- K3: E[c][d] = sum_z (g1+g2), mirrored to E[d][c] ----------------
// 136 upper 64x64 tiles; pair tile located in compact per-pair storage.
__global__ __launch_bounds__(256) void k_reduce(const float* __restrict__ g1,
                                                const float* __restrict__ g2,
                                                float* __restrict__ E,
                                                int splitk) {
    __shared__ float ld[64][65];
    const int t = threadIdx.x;
    const int i = t >> 2;              // row 0..63
    const int jb = (t & 3) << 4;       // col chunk base 0/16/32/48

    // tile decode: blockIdx.x in [0,136) -> (cb <= db) over 16x16 64-tiles
    int pr = blockIdx.x, ci = 0;
    while (pr >= 16 - ci) { pr -= 16 - ci; ++ci; }
    const int cb = ci, db = ci + pr;
    const int i8 = cb >> 1, j8 = db >> 1;
    const int p = i8 * (17 - i8) / 2 + (j8 - i8);    // pair index of 128-block
    const size_t tbase = ((size_t)p << 14) + ((size_t)(cb & 1) << 13) + ((size_t)(db & 1) << 6);

    float acc[16];
#pragma unroll
    for (int u = 0; u < 16; ++u) acc[u] = 0.0f;

    for (int z = 0; z < splitk; ++z) {
        const size_t zo = (size_t)z * (36 << 14) + tbase + ((size_t)i << 7) + jb;
        const float* p1 = g1 + zo;
        const float* p2 = g2 + zo;
#pragma unroll
        for (int u4 = 0; u4 < 4; ++u4) {
            float4 v1 = ((const float4*)p1)[u4];
            float4 v2 = ((const float4*)p2)[u4];
            acc[u4 * 4 + 0] += v1.x + v2.x;
            acc[u4 * 4 + 1] += v1.y + v2.y;
            acc[u4 * 4 + 2] += v1.z + v2.z;
            acc[u4 * 4 + 3] += v1.w + v2.w;
        }
    }

    // direct (upper) write
    float* eo = E + ((size_t)((cb << 6) + i) << 10) + (db << 6) + jb;
#pragma unroll
    for (int u4 = 0; u4 < 4; ++u4) {
        float4 v;
        v.x = acc[u4 * 4 + 0]; v.y = acc[u4 * 4 + 1];
        v.z = acc[u4 * 4 + 2]; v.w = acc[u4 * 4 + 3];
        ((float4*)eo)[u4] = v;
    }

    if (cb != db) {   // mirrored (lower) write via LDS transpose
#pragma unroll
        for (int u4 = 0; u4 < 4; ++u4)
            *(float4*)&ld[i][jb + u4 * 4] = *(float4*)&acc[u4 * 4];
        __syncthreads();
        float tmp[16];
#pragma unroll
        for (int u = 0; u < 16; ++u) tmp[u] = ld[jb + u][i];
        float* et = E + ((size_t)((db << 6) + i) << 10) + (cb << 6) + jb;
#pragma unroll
        for (int u4 = 0; u4 < 4; ++u4)
            ((float4*)et)[u4] = *(float4*)&tmp[u4 * 4];
    }
}

// ---------------- K4: row softmax: A = softmax(rowmin(E) - E) ----------------
__global__ __launch_bounds__(256) void k_softmax(const float* __restrict__ E,
                                                 ushort_t* __restrict__ att) {
    const int c = blockIdx.x;
    const int t = threadIdx.x;
    __shared__ float red[4];
    __shared__ float bcast;

    float4 e4 = ((const float4*)E)[((size_t)c << 8) + t];
    float m = fminf(fminf(e4.x, e4.y), fminf(e4.z, e4.w));
#pragma unroll
    for (int off = 32; off > 0; off >>= 1) m = fminf(m, __shfl_down(m, off));
    if ((t & 63) == 0) red[t >> 6] = m;
    __syncthreads();
    if (t == 0) bcast = fminf(fminf(red[0], red[1]), fminf(red[2], red[3]));
    __syncthreads();
    m = bcast;

    float w0 = expf(m - e4.x), w1 = expf(m - e4.y);
    float w2 = expf(m - e4.z), w3 = expf(m - e4.w);
    float s = w0 + w1 + w2 + w3;
#pragma unroll
    for (int off = 32; off > 0; off >>= 1) s += __shfl_down(s, off);
    if ((t & 63) == 0) red[t >> 6] = s;
    __syncthreads();
    if (t == 0) bcast = red[0] + red[1] + red[2] + red[3];
    __syncthreads();
    float inv = 1.0f / bcast;
    ushort4 o;
    o.x = f2b(w0 * inv); o.y = f2b(w1 * inv);
    o.z = f2b(w2 * inv); o.w = f2b(w3 * inv);
    ((ushort4*)att)[((size_t)c << 8) + t] = o;
}

// ---------------- K5 (fallback): transpose Ph -> PhT ----------------
__global__ __launch_bounds__(256) void k_transpose(const ushort_t* __restrict__ ph,
                                                   ushort_t* __restrict__ pht) {
    __shared__ __align__(16) ushort_t tile[64][72];
    const int t = threadIdx.x;
    const int i = t >> 2, qd = t & 3;
    const int c0 = blockIdx.y << 6;
    const size_t n0 = (size_t)blockIdx.x << 6;

    const ushort_t* src = ph + (size_t)(c0 + i) * N_DIM + n0 + (qd << 4);
    uint4 v0 = *(const uint4*)src;
    uint4 v1 = *(const uint4*)(src + 8);
    *(uint4*)&tile[i][qd << 4]       = v0;
    *(uint4*)&tile[i][(qd << 4) + 8] = v1;
    __syncthreads();

    ushort_t tmp[16];
#pragma unroll
    for (int u = 0; u < 16; ++u) tmp[u] = tile[(qd << 4) + u][i];
    ushort_t* dst = pht + (n0 + i) * C_DIM + c0 + (qd << 4);
    *(uint4*)dst       = *(uint4*)tmp;
    *(uint4*)(dst + 8) = *(uint4*)(tmp + 8);
}

// ---------------- K6: O = A * P, out = gamma*O + x. 128x128 tile, 4 waves of 64x64 ----------------
// double-buffered LDS + raw barriers + counted vmcnt (prefetch never drained)
__global__ __launch_bounds__(256) void k_ogemm(const ushort_t* __restrict__ att,
                                               const ushort_t* __restrict__ pht,
                                               const float* __restrict__ x,
                                               const float* __restrict__ gamma,
                                               float* __restrict__ out) {
    __shared__ __align__(16) ushort_t sA[2][128 * 32];
    __shared__ __align__(16) ushort_t sB[2][128 * 32];

    const int t = threadIdx.x;
    const int w = t >> 6, L = t & 63;
    const int n0 = blockIdx.x << 7;
    const int c0 = blockIdx.y << 7;
    const int srow = L >> 2;
    const int scol = (((L & 3) ^ ((L >> 3) & 3)) << 3);   // swizzled source segment

    const int wm = (w >> 1) << 6, wn = (w & 1) << 6;
    const int lm = L & 15, q = L >> 4;
    const int co = ((q ^ ((lm >> 1) & 3)) << 3);          // swizzled read segment

    f32x4 acc[4][4];
#pragma unroll
    for (int a = 0; a < 4; ++a)
#pragma unroll
        for (int b = 0; b < 4; ++b) acc[a][b] = (f32x4)0.0f;

    auto stage = [&](int k0, int b) {
#pragma unroll
        for (int j = 0; j < 4; ++j) {
            int ch = (w << 2) + j;                    // 0..7 -> sA rows, 8..15 -> sB rows
            int row = ((ch & 7) << 4) + srow;
            const ushort_t* src = (ch < 8)
                ? att + (size_t)(c0 + row) * C_DIM + k0 + scol
                : pht + (size_t)(n0 + row) * C_DIM + k0 + scol;
            ushort_t* base = (ch < 8) ? sA[b] : sB[b];
            async16(src, base + (((ch & 7) << 4) << 5));
        }
    };

    const int nIter = C_DIM / 32;   // 32
    stage(0, 0);

    for (int ti = 0; ti < nIter; ++ti) {
        const int cb = ti & 1;
        if (ti + 1 < nIter) {
            stage((ti + 1) << 5, cb ^ 1);
            __builtin_amdgcn_s_waitcnt(0x0F74);   // vmcnt(4): tile ti landed; prefetch in flight
        } else {
            __builtin_amdgcn_s_waitcnt(0x0F70);   // vmcnt(0)
        }
        __builtin_amdgcn_s_barrier();

        bf16x8 a[4], b[4];
#pragma unroll
        for (int mt = 0; mt < 4; ++mt)
            a[mt] = *(const bf16x8*)(sA[cb] + ((wm + (mt << 4) + lm) << 5) + co);
#pragma unroll
        for (int nt = 0; nt < 4; ++nt)
            b[nt] = *(const bf16x8*)(sB[cb] + ((wn + (nt << 4) + lm) << 5) + co);
#pragma unroll
        for (int mt = 0; mt < 4; ++mt)
#pragma unroll
            for (int nt = 0; nt < 4; ++nt)
                acc[mt][nt] = __builtin_amdgcn_mfma_f32_16x16x32_bf16(a[mt], b[nt], acc[mt][nt], 0, 0, 0);
        __builtin_amdgcn_s_barrier();
    }

    const float g = gamma[0];
#pragma unroll
    for (int mt = 0; mt < 4; ++mt)
#pragma unroll
        for (int nt = 0; nt < 4; ++nt)
#pragma unroll
            for (int r = 0; r < 4; ++r) {
                int cg = c0 + wm + (mt << 4) + (q << 2) + r;
                int ng = n0 + wn + (nt << 4) + lm;
                size_t o = (size_t)cg * N_DIM + ng;
                out[o] = g * acc[mt][nt][r] + x[o];
            }
}

extern "C" void kernel_launch(void* const* d_in, const int* in_sizes, int n_in,
                              void* d_out, int out_size, void* d_ws, size_t ws_size,
                              hipStream_t stream) {
    const float* x     = (const float*)d_in[0];
    const float* gamma = (const float*)d_in[1];
    float* out = (float*)d_out;
    char* ws = (char*)d_ws;

    const size_t P  = 75497472ull;          // 72 MB bf16 plane
    const size_t GT = 2359296ull;           // compact G bytes per z (36 * 128*128 * 4)
    const size_t EB = 4194304ull, AT = 2097152ull;

    auto need = [&](int s, bool f) {
        return (size_t)(f ? 3 : 2) * P + (size_t)s * 2 * GT + EB + AT;
    };

    // S must divide 1152 k-steps: {12, 8, 4}
    int S = 12;
    bool fused = true;
    if (ws_size < need(12, true)) {
        if      (ws_size >= need(8, true)) S = 8;
        else if (ws_size >= need(4, true)) S = 4;
        else {
            fused = false; S = 12;
            if (ws_size < need(12, false)) S = 8;
            if (ws_size < need(8,  false)) S = 4;
        }
    }
    const int kchunk = N_DIM / S;

    if (fused) {
        ushort_t* ph  = (ushort_t*)(ws);
        ushort_t* pl  = (ushort_t*)(ws + P);
        ushort_t* pht = (ushort_t*)(ws + 2 * P);
        float*    g1  = (float*)   (ws + 3 * P);
        float*    g2  = (float*)   (ws + 3 * P + (size_t)S * GT);
        float*    E   = (float*)   (ws + 3 * P + (size_t)S * 2 * GT);
        ushort_t* att = (ushort_t*)(ws + 3 * P + (size_t)S * 2 * GT + EB);

        k_convtrans<<<dim3(N_DIM / 64, C_DIM / 64), 256, 0, stream>>>(x, ph, pl, pht);
        k_egemm<<<dim3(36, 1, S), 256, 0, stream>>>(ph, pl, g1, g2, kchunk);
        k_reduce<<<dim3(136), 256, 0, stream>>>(g1, g2, E, S);
        k_softmax<<<dim3(C_DIM), 256, 0, stream>>>(E, att);
        k_ogemm<<<dim3(N_DIM / 128, C_DIM / 128), 256, 0, stream>>>(att, pht, x, gamma, out);
    } else {
        ushort_t* ph  = (ushort_t*)(ws);
        ushort_t* pl  = (ushort_t*)(ws + P);
        float*    g1  = (float*)   (ws + 2 * P);
        float*    g2  = (float*)   (ws + 2 * P + (size_t)S * GT);
        float*    E   = (float*)   (ws + 2 * P + (size_t)S * 2 * GT);
        ushort_t* att = (ushort_t*)(ws + 2 * P + (size_t)S * 2 * GT + EB);
        ushort_t* pht = pl;   // transpose written after E-GEMM has consumed Pl

        k_convert<<<dim3((C_DIM * (size_t)N_DIM / 4) / 256), 256, 0, stream>>>(x, ph, pl);
        k_egemm<<<dim3(36, 1, S), 256, 0, stream>>>(ph, pl, g1, g2, kchunk);
        k_reduce<<<dim3(136), 256, 0, stream>>>(g1, g2, E, S);
        k_softmax<<<dim3(C_DIM), 256, 0, stream>>>(E, att);
        k_transpose<<<dim3(N_DIM / 64, C_DIM / 64), 256, 0, stream>>>(ph, pht);
        k_ogemm<<<dim3(N_DIM / 128, C_DIM / 128), 256, 0, stream>>>(att, pht, x, gamma, out);
    }
}

// Round 3
// 584.975 us; speedup vs baseline: 1.1661x; 1.0742x over previous
//
#include <hip/hip_runtime.h>
#include <cstdint>

#define C_DIM 1024
#define N_DIM 36864   // 192*192

typedef unsigned short ushort_t;
typedef __attribute__((ext_vector_type(8))) short bf16x8;   // 8 bf16 in 4 VGPRs
typedef __attribute__((ext_vector_type(4))) float f32x4;

__device__ __forceinline__ ushort_t f2b(float f) {
    unsigned u = __float_as_uint(f);
    u = (u + 0x7fffu + ((u >> 16) & 1u)) >> 16;   // RN-even
    return (ushort_t)u;
}
__device__ __forceinline__ float b2f(ushort_t b) {
    return __uint_as_float(((unsigned)b) << 16);
}

// async global->LDS, 16B per lane; lds base must be wave-uniform, HW adds lane*16
__device__ __forceinline__ void async16(const void* g, const void* lds) {
    __builtin_amdgcn_global_load_lds(
        (const __attribute__((address_space(1))) unsigned int*)(uintptr_t)g,
        (__attribute__((address_space(3))) unsigned int*)(uint32_t)(uintptr_t)lds,
        16, 0, 0);
}

// LDS tile layout for GEMM operands: [rows][32] ushorts (64 B rows).
// Bank-conflict swizzle: 16B segment s of row r lives at segment (s ^ ((r>>1)&3)).
// global_load_lds writes linearly, so we pre-permute the GLOBAL source column per
// lane (segments permuted within the same 64B row -> coalescing unchanged) and
// apply the same XOR on the ds_read side.  8-way conflict -> 2-way (free).

// ---------------- K1a (fallback): x -> Ph, Pl ----------------
__global__ __launch_bounds__(256) void k_convert(const float* __restrict__ x,
                                                 ushort_t* __restrict__ ph,
                                                 ushort_t* __restrict__ pl) {
    int i = blockIdx.x * 256 + threadIdx.x;        // float4 index
    float4 v = ((const float4*)x)[i];
    ushort4 h, l;
    h.x = f2b(v.x); l.x = f2b(v.x - b2f(h.x));
    h.y = f2b(v.y); l.y = f2b(v.y - b2f(h.y));
    h.z = f2b(v.z); l.z = f2b(v.z - b2f(h.z));
    h.w = f2b(v.w); l.w = f2b(v.w - b2f(h.w));
    ((ushort4*)ph)[i] = h;
    ((ushort4*)pl)[i] = l;
}

// ---------------- K1b (preferred): x -> Ph, Pl, PhT in one pass ----------------
__global__ __launch_bounds__(256) void k_convtrans(const float* __restrict__ x,
                                                   ushort_t* __restrict__ ph,
                                                   ushort_t* __restrict__ pl,
                                                   ushort_t* __restrict__ pht) {
    __shared__ __align__(16) ushort_t th[64][72];
    const int t = threadIdx.x;
    const int i = t >> 2, qd = t & 3;
    const int c0 = blockIdx.y << 6;
    const size_t n0 = (size_t)blockIdx.x << 6;

    const size_t row = (size_t)(c0 + i) * N_DIM + n0 + (qd << 4);
    const float* src = x + row;
    union { ushort_t s[16]; uint4 q[2]; } H, Lo;
#pragma unroll
    for (int u4 = 0; u4 < 4; ++u4) {
        float4 v = ((const float4*)src)[u4];
        ushort_t h0 = f2b(v.x), h1 = f2b(v.y), h2 = f2b(v.z), h3 = f2b(v.w);
        H.s[u4 * 4 + 0] = h0; Lo.s[u4 * 4 + 0] = f2b(v.x - b2f(h0));
        H.s[u4 * 4 + 1] = h1; Lo.s[u4 * 4 + 1] = f2b(v.y - b2f(h1));
        H.s[u4 * 4 + 2] = h2; Lo.s[u4 * 4 + 2] = f2b(v.z - b2f(h2));
        H.s[u4 * 4 + 3] = h3; Lo.s[u4 * 4 + 3] = f2b(v.w - b2f(h3));
    }
    *(uint4*)(ph + row)     = H.q[0];
    *(uint4*)(ph + row + 8) = H.q[1];
    *(uint4*)(pl + row)     = Lo.q[0];
    *(uint4*)(pl + row + 8) = Lo.q[1];
    *(uint4*)&th[i][qd << 4]       = H.q[0];
    *(uint4*)&th[i][(qd << 4) + 8] = H.q[1];
    __syncthreads();

    ushort_t tmp[16];
#pragma unroll
    for (int u = 0; u < 16; ++u) tmp[u] = th[(qd << 4) + u][i];
    ushort_t* dst = pht + (n0 + i) * C_DIM + c0 + (qd << 4);
    *(uint4*)dst       = *(uint4*)tmp;
    *(uint4*)(dst + 8) = *(uint4*)(tmp + 8);
}

// ---------------- K2: triangular E-GEMM partials over 36 tile-pairs ----------------
// E = Ph*Ph^T + (Ph*Pl^T + Pl*Ph^T); both addends symmetric -> only upper pairs.
// Per pair (c0<=d0): acc1 = Ph_c*Ph_d^T, acc2 = Ph_c*Pl_d^T + Pl_c*Ph_d^T.
// tile 128x128, BK=32, 4 waves of 64x64, 3 MFMA chains, split-K (z from flat grid).
// XCD-aware dispatch: flat id -> xcd = id&7; each XCD gets a contiguous lex chunk
// of 4-5 pairs per z (pairs sharing row-panels land in the same XCD L2).
// Compact output: g[(z*36+pair)*16384 + r*128 + c].
__global__ __launch_bounds__(256, 2) void k_egemm(const ushort_t* __restrict__ ph,
                                                  const ushort_t* __restrict__ pl,
                                                  float* __restrict__ g1,
                                                  float* __restrict__ g2,
                                                  int kchunk) {
    __shared__ __align__(16) ushort_t sAh[2][128 * 32];   // 16 KB each
    __shared__ __align__(16) ushort_t sAl[2][128 * 32];
    __shared__ __align__(16) ushort_t sBh[2][128 * 32];
    __shared__ __align__(16) ushort_t sBl[2][128 * 32];   // 64 KB total -> 2 blocks/CU

    // ---- dispatch decode: 40 slots per z (chunks 0-3: 5 pairs, 4-7: 4 pairs) ----
    const int f   = blockIdx.x;
    const int xcd = f & 7;
    const int r   = f >> 3;
    const int z   = r / 5;
    const int s   = r - z * 5;
    const int chunk = (xcd + ((z & 1) << 2)) & 7;   // rotate by z parity -> balance
    if (chunk >= 4 && s == 4) return;               // dummy slot
    const int u = (chunk < 4) ? (chunk * 5 + s) : (20 + (chunk - 4) * 4 + s);

    int pr = u, pi = 0;
    while (pr >= 8 - pi) { pr -= 8 - pi; ++pi; }
    const int c0 = pi << 7;
    const int d0 = (pi + pr) << 7;

    const int t = threadIdx.x;
    const int w = t >> 6;
    const int L = t & 63;

    const int kb = z * kchunk;
    const int lrow = L >> 2;
    const int lcol = (((L & 3) ^ ((L >> 3) & 3)) << 3);   // pre-swizzled source segment

    const size_t rA = (size_t)(c0 + (w << 5) + lrow) * N_DIM + kb + lcol;
    const size_t rB = (size_t)(d0 + (w << 5) + lrow) * N_DIM + kb + lcol;
    const ushort_t* gAh = ph + rA;
    const ushort_t* gAl = pl + rA;
    const ushort_t* gBh = ph + rB;
    const ushort_t* gBl = pl + rB;
    const int wb = w << 10;   // wave's 32-row slice in each LDS panel

    const int wm = (w >> 1) << 6;   // wave row offset (c) 0/64
    const int wn = (w & 1) << 6;    // wave col offset (d) 0/64
    const int lm = L & 15, q = L >> 4;
    const int co = ((q ^ ((lm >> 1) & 3)) << 3);   // swizzled k-segment for reads

    f32x4 acc1[4][4], acc2[4][4];
#pragma unroll
    for (int a = 0; a < 4; ++a)
#pragma unroll
        for (int b = 0; b < 4; ++b) { acc1[a][b] = (f32x4)0.0f; acc2[a][b] = (f32x4)0.0f; }

    auto stage = [&](int ti, int b) {
        const int o = ti << 5;
        async16(gAh + o,              sAh[b] + wb);
        async16(gAh + o + 16 * N_DIM, sAh[b] + wb + 512);
        async16(gAl + o,              sAl[b] + wb);
        async16(gAl + o + 16 * N_DIM, sAl[b] + wb + 512);
        async16(gBh + o,              sBh[b] + wb);
        async16(gBh + o + 16 * N_DIM, sBh[b] + wb + 512);
        async16(gBl + o,              sBl[b] + wb);
        async16(gBl + o + 16 * N_DIM, sBl[b] + wb + 512);
    };

    const int nIter = kchunk >> 5;
    stage(0, 0);

    for (int ti = 0; ti < nIter; ++ti) {
        const int cb = ti & 1;
        if (ti + 1 < nIter) {
            stage(ti + 1, cb ^ 1);
            __builtin_amdgcn_s_waitcnt(0x0F78);   // vmcnt(8): tile ti landed; prefetch in flight
        } else {
            __builtin_amdgcn_s_waitcnt(0x0F70);   // vmcnt(0): last tile landed
        }
        __builtin_amdgcn_s_barrier();

        bf16x8 ah[4], al[4], bh[4], bl[4];
#pragma unroll
        for (int mt = 0; mt < 4; ++mt) {
            const int ro = ((wm + (mt << 4) + lm) << 5) + co;
            ah[mt] = *(const bf16x8*)(sAh[cb] + ro);
            al[mt] = *(const bf16x8*)(sAl[cb] + ro);
        }
#pragma unroll
        for (int nt = 0; nt < 4; ++nt) {
            const int ro = ((wn + (nt << 4) + lm) << 5) + co;
            bh[nt] = *(const bf16x8*)(sBh[cb] + ro);
            bl[nt] = *(const bf16x8*)(sBl[cb] + ro);
        }
#pragma unroll
        for (int mt = 0; mt < 4; ++mt)
#pragma unroll
            for (int nt = 0; nt < 4; ++nt) {
                acc1[mt][nt] = __builtin_amdgcn_mfma_f32_16x16x32_bf16(ah[mt], bh[nt], acc1[mt][nt], 0, 0, 0);
                acc2[mt][nt] = __builtin_amdgcn_mfma_f32_16x16x32_bf16(ah[mt], bl[nt], acc2[mt][nt], 0, 0, 0);
                acc2[mt][nt] = __builtin_amdgcn_mfma_f32_16x16x32_bf16(al[mt], bh[nt], acc2[mt][nt], 0, 0, 0);
            }
        __builtin_amdgcn_s_barrier();
    }

    const size_t base = ((size_t)z * 36 + u) << 14;
#pragma unroll
    for (int mt = 0; mt < 4; ++mt)
#pragma unroll
        for (int nt = 0; nt < 4; ++nt)
#pragma unroll
            for (int r2 = 0; r2 < 4; ++r2) {
                int lr = wm + (mt << 4) + (q << 2) + r2;   // row within 128-tile (c)
                int lc = wn + (nt << 4) + lm;              // col within 128-tile (d)
                size_t o = base + ((size_t)lr << 7) + lc;
                g1[o] = acc1[mt][nt][r2];
                g2[o] = acc2[mt][nt][r2];
            }
}

// ---------------- K3: E[c][d] = sum_z (g1+g2), mirrored to E[d][c] ----------------
// 136 upper 64x64 tiles; pair tile located in compact per-pair storage.
__global__ __launch_bounds__(256) void k_reduce(const float* __restrict__ g1,
                                                const float* __restrict__ g2,
                                                float* __restrict__ E,
                                                int splitk) {
    __shared__ float ld[64][65];
    const int t = threadIdx.x;
    const int i = t >> 2;              // row 0..63
    const int jb = (t & 3) << 4;       // col chunk base 0/16/32/48

    // tile decode: blockIdx.x in [0,136) -> (cb <= db) over 16x16 64-tiles
    int pr = blockIdx.x, ci = 0;
    while (pr >= 16 - ci) { pr -= 16 - ci; ++ci; }
    const int cb = ci, db = ci + pr;
    const int i8 = cb >> 1, j8 = db >> 1;
    const int p = i8 * (17 - i8) / 2 + (j8 - i8);    // pair index of 128-block
    const size_t tbase = ((size_t)p << 14) + ((size_t)(cb & 1) << 13) + ((size_t)(db & 1) << 6);

    float acc[16];
#pragma unroll
    for (int u = 0; u < 16; ++u) acc[u] = 0.0f;

    for (int z = 0; z < splitk; ++z) {
        const size_t zo = (size_t)z * (36 << 14) + tbase + ((size_t)i << 7) + jb;
        const float* p1 = g1 + zo;
        const float* p2 = g2 + zo;
#pragma unroll
        for (int u4 = 0; u4 < 4; ++u4) {
            float4 v1 = ((const float4*)p1)[u4];
            float4 v2 = ((const float4*)p2)[u4];
            acc[u4 * 4 + 0] += v1.x + v2.x;
            acc[u4 * 4 + 1] += v1.y + v2.y;
            acc[u4 * 4 + 2] += v1.z + v2.z;
            acc[u4 * 4 + 3] += v1.w + v2.w;
        }
    }

    // direct (upper) write
    float* eo = E + ((size_t)((cb << 6) + i) << 10) + (db << 6) + jb;
#pragma unroll
    for (int u4 = 0; u4 < 4; ++u4) {
        float4 v;
        v.x = acc[u4 * 4 + 0]; v.y = acc[u4 * 4 + 1];
        v.z = acc[u4 * 4 + 2]; v.w = acc[u4 * 4 + 3];
        ((float4*)eo)[u4] = v;
    }

    if (cb != db) {   // mirrored (lower) write via LDS transpose
#pragma unroll
        for (int u4 = 0; u4 < 4; ++u4)
            *(float4*)&ld[i][jb + u4 * 4] = *(float4*)&acc[u4 * 4];
        __syncthreads();
        float tmp[16];
#pragma unroll
        for (int u = 0; u < 16; ++u) tmp[u] = ld[jb + u][i];
        float* et = E + ((size_t)((db << 6) + i) << 10) + (cb << 6) + jb;
#pragma unroll
        for (int u4 = 0; u4 < 4; ++u4)
            ((float4*)et)[u4] = *(float4*)&tmp[u4 * 4];
    }
}

// ---------------- K4: row softmax: A = softmax(rowmin(E) - E) ----------------
__global__ __launch_bounds__(256) void k_softmax(const float* __restrict__ E,
                                                 ushort_t* __restrict__ att) {
    const int c = blockIdx.x;
    const int t = threadIdx.x;
    __shared__ float red[4];
    __shared__ float bcast;

    float4 e4 = ((const float4*)E)[((size_t)c << 8) + t];
    float m = fminf(fminf(e4.x, e4.y), fminf(e4.z, e4.w));
#pragma unroll
    for (int off = 32; off > 0; off >>= 1) m = fminf(m, __shfl_down(m, off));
    if ((t & 63) == 0) red[t >> 6] = m;
    __syncthreads();
    if (t == 0) bcast = fminf(fminf(red[0], red[1]), fminf(red[2], red[3]));
    __syncthreads();
    m = bcast;

    float w0 = expf(m - e4.x), w1 = expf(m - e4.y);
    float w2 = expf(m - e4.z), w3 = expf(m - e4.w);
    float s = w0 + w1 + w2 + w3;
#pragma unroll
    for (int off = 32; off > 0; off >>= 1) s += __shfl_down(s, off);
    if ((t & 63) == 0) red[t >> 6] = s;
    __syncthreads();
    if (t == 0) bcast = red[0] + red[1] + red[2] + red[3];
    __syncthreads();
    float inv = 1.0f / bcast;
    ushort4 o;
    o.x = f2b(w0 * inv); o.y = f2b(w1 * inv);
    o.z = f2b(w2 * inv); o.w = f2b(w3 * inv);
    ((ushort4*)att)[((size_t)c << 8) + t] = o;
}

// ---------------- K5 (fallback): transpose Ph -> PhT ----------------
__global__ __launch_bounds__(256) void k_transpose(const ushort_t* __restrict__ ph,
                                                   ushort_t* __restrict__ pht) {
    __shared__ __align__(16) ushort_t tile[64][72];
    const int t = threadIdx.x;
    const int i = t >> 2, qd = t & 3;
    const int c0 = blockIdx.y << 6;
    const size_t n0 = (size_t)blockIdx.x << 6;

    const ushort_t* src = ph + (size_t)(c0 + i) * N_DIM + n0 + (qd << 4);
    uint4 v0 = *(const uint4*)src;
    uint4 v1 = *(const uint4*)(src + 8);
    *(uint4*)&tile[i][qd << 4]       = v0;
    *(uint4*)&tile[i][(qd << 4) + 8] = v1;
    __syncthreads();

    ushort_t tmp[16];
#pragma unroll
    for (int u = 0; u < 16; ++u) tmp[u] = tile[(qd << 4) + u][i];
    ushort_t* dst = pht + (n0 + i) * C_DIM + c0 + (qd << 4);
    *(uint4*)dst       = *(uint4*)tmp;
    *(uint4*)(dst + 8) = *(uint4*)(tmp + 8);
}

// ---------------- K6: O = A * P, out = gamma*O + x ----------------
// tile 128(c) x 256(n), 4 waves of 64x128, BK=32, dbuf + counted vmcnt.
// XCD-aware dispatch: the 8 c-blocks of one n-strip sit consecutively within one
// XCD's queue (d = 64a + 8c + xcd) -> PhT n-panel fetched ~once instead of 8x.
__global__ __launch_bounds__(256, 2) void k_ogemm(const ushort_t* __restrict__ att,
                                                  const ushort_t* __restrict__ pht,
                                                  const float* __restrict__ x,
                                                  const float* __restrict__ gamma,
                                                  float* __restrict__ out) {
    __shared__ __align__(16) ushort_t sA[2][128 * 32];   // 16 KB
    __shared__ __align__(16) ushort_t sB[2][256 * 32];   // 32 KB

    const int d   = blockIdx.x;          // 0..1151
    const int xcd = d & 7;
    const int r   = d >> 3;              // 0..143
    const int a0  = r >> 3;              // 0..17
    const int cbk = r & 7;               // 0..7
    const int n0 = (xcd * 18 + a0) << 8; // 256-wide n strip
    const int c0 = cbk << 7;

    const int t = threadIdx.x;
    const int w = t >> 6, L = t & 63;
    const int srow = L >> 2;
    const int scol = (((L & 3) ^ ((L >> 3) & 3)) << 3);   // swizzled source segment

    const int wm = (w >> 1) << 6;        // wave c offset 0/64
    const int wn = (w & 1) << 7;         // wave n offset 0/128
    const int lm = L & 15, q = L >> 4;
    const int co = ((q ^ ((lm >> 1) & 3)) << 3);          // swizzled read segment

    f32x4 acc[4][8];
#pragma unroll
    for (int a = 0; a < 4; ++a)
#pragma unroll
        for (int b = 0; b < 8; ++b) acc[a][b] = (f32x4)0.0f;

    auto stage = [&](int k0, int b) {
#pragma unroll
        for (int j = 0; j < 6; ++j) {
            int ch = w * 6 + j;                       // 0..23: 0-7 -> sA, 8-23 -> sB
            const ushort_t* src;
            ushort_t* base;
            if (ch < 8) {
                src = att + (size_t)(c0 + (ch << 4) + srow) * C_DIM + k0 + scol;
                base = sA[b] + (ch << 9);
            } else {
                int rb = ch - 8;
                src = pht + (size_t)(n0 + (rb << 4) + srow) * C_DIM + k0 + scol;
                base = sB[b] + (rb << 9);
            }
            async16(src, base);
        }
    };

    const int nIter = C_DIM / 32;   // 32
    stage(0, 0);

    for (int ti = 0; ti < nIter; ++ti) {
        const int cb = ti & 1;
        if (ti + 1 < nIter) {
            stage((ti + 1) << 5, cb ^ 1);
            __builtin_amdgcn_s_waitcnt(0x0F76);   // vmcnt(6): tile ti landed; prefetch in flight
        } else {
            __builtin_amdgcn_s_waitcnt(0x0F70);   // vmcnt(0)
        }
        __builtin_amdgcn_s_barrier();

        bf16x8 a[4], b[8];
#pragma unroll
        for (int mt = 0; mt < 4; ++mt)
            a[mt] = *(const bf16x8*)(sA[cb] + ((wm + (mt << 4) + lm) << 5) + co);
#pragma unroll
        for (int nt = 0; nt < 8; ++nt)
            b[nt] = *(const bf16x8*)(sB[cb] + ((wn + (nt << 4) + lm) << 5) + co);
#pragma unroll
        for (int mt = 0; mt < 4; ++mt)
#pragma unroll
            for (int nt = 0; nt < 8; ++nt)
                acc[mt][nt] = __builtin_amdgcn_mfma_f32_16x16x32_bf16(a[mt], b[nt], acc[mt][nt], 0, 0, 0);
        __builtin_amdgcn_s_barrier();
    }

    const float g = gamma[0];
#pragma unroll
    for (int mt = 0; mt < 4; ++mt)
#pragma unroll
        for (int nt = 0; nt < 8; ++nt)
#pragma unroll
            for (int r2 = 0; r2 < 4; ++r2) {
                int cg = c0 + wm + (mt << 4) + (q << 2) + r2;
                int ng = n0 + wn + (nt << 4) + lm;
                size_t o = (size_t)cg * N_DIM + ng;
                out[o] = g * acc[mt][nt][r2] + x[o];
            }
}

extern "C" void kernel_launch(void* const* d_in, const int* in_sizes, int n_in,
                              void* d_out, int out_size, void* d_ws, size_t ws_size,
                              hipStream_t stream) {
    const float* x     = (const float*)d_in[0];
    const float* gamma = (const float*)d_in[1];
    float* out = (float*)d_out;
    char* ws = (char*)d_ws;

    const size_t P  = 75497472ull;          // 72 MB bf16 plane
    const size_t GT = 2359296ull;           // compact G bytes per z (36 * 128*128 * 4)
    const size_t EB = 4194304ull, AT = 2097152ull;

    auto need = [&](int s, bool f) {
        return (size_t)(f ? 3 : 2) * P + (size_t)s * 2 * GT + EB + AT;
    };

    // S must divide 1152 k-steps: {12, 8, 4}
    int S = 12;
    bool fused = true;
    if (ws_size < need(12, true)) {
        if      (ws_size >= need(8, true)) S = 8;
        else if (ws_size >= need(4, true)) S = 4;
        else {
            fused = false; S = 12;
            if (ws_size < need(12, false)) S = 8;
            if (ws_size < need(8,  false)) S = 4;
        }
    }
    const int kchunk = N_DIM / S;

    if (fused) {
        ushort_t* ph  = (ushort_t*)(ws);
        ushort_t* pl  = (ushort_t*)(ws + P);
        ushort_t* pht = (ushort_t*)(ws + 2 * P);
        float*    g1  = (float*)   (ws + 3 * P);
        float*    g2  = (float*)   (ws + 3 * P + (size_t)S * GT);
        float*    E   = (float*)   (ws + 3 * P + (size_t)S * 2 * GT);
        ushort_t* att = (ushort_t*)(ws + 3 * P + (size_t)S * 2 * GT + EB);

        k_convtrans<<<dim3(N_DIM / 64, C_DIM / 64), 256, 0, stream>>>(x, ph, pl, pht);
        k_egemm<<<dim3(40 * S), 256, 0, stream>>>(ph, pl, g1, g2, kchunk);
        k_reduce<<<dim3(136), 256, 0, stream>>>(g1, g2, E, S);
        k_softmax<<<dim3(C_DIM), 256, 0, stream>>>(E, att);
        k_ogemm<<<dim3(1152), 256, 0, stream>>>(att, pht, x, gamma, out);
    } else {
        ushort_t* ph  = (ushort_t*)(ws);
        ushort_t* pl  = (ushort_t*)(ws + P);
        float*    g1  = (float*)   (ws + 2 * P);
        float*    g2  = (float*)   (ws + 2 * P + (size_t)S * GT);
        float*    E   = (float*)   (ws + 2 * P + (size_t)S * 2 * GT);
        ushort_t* att = (ushort_t*)(ws + 2 * P + (size_t)S * 2 * GT + EB);
        ushort_t* pht = pl;   // transpose written after E-GEMM has consumed Pl

        k_convert<<<dim3((C_DIM * (size_t)N_DIM / 4) / 256), 256, 0, stream>>>(x, ph, pl);
        k_egemm<<<dim3(40 * S), 256, 0, stream>>>(ph, pl, g1, g2, kchunk);
        k_reduce<<<dim3(136), 256, 0, stream>>>(g1, g2, E, S);
        k_softmax<<<dim3(C_DIM), 256, 0, stream>>>(E, att);
        k_transpose<<<dim3(N_DIM / 64, C_DIM / 64), 256, 0, stream>>>(ph, pht);
        k_ogemm<<<dim3(1152), 256, 0, stream>>>(att, pht, x, gamma, out);
    }
}